// Round 5
// baseline (382.205 us; speedup 1.0000x reference)
//
#include <hip/hip_runtime.h>
#include <float.h>
#include <stdint.h>

// StatisticExtractor: B=128, C=32, L=8192.
// One 1024-thread block per (b,c) row. Row held in REGISTERS (2 float4/thread,
// chunked-coalesced). Invalid -> FLT_MAX sentinel, which participates in the
// quantile path exactly like the reference's where(m>0, x, fmax) fill.
// Exact quantiles: 4096-bin monotone bit-key histogram -> shuffle scan ->
// gather target bins -> O(k^2) counting-rank select; radix fallback.

#define L_LEN 8192
#define NT    1024
#define NB    4096   // histogram bins (top 12 bits of flipped float key)
#define CAP   256    // max gathered candidates per target bin
#define FMAX  FLT_MAX

__device__ __forceinline__ uint32_t fkey(float x) {
    uint32_t u = __float_as_uint(x);
    return (u & 0x80000000u) ? ~u : (u | 0x80000000u);   // monotone total order
}

__global__ __launch_bounds__(NT, 8)
void stats_kernel(const float* __restrict__ data,
                  const int* __restrict__ mask,
                  float* __restrict__ out)
{
    __shared__ __align__(16) uint32_t s_hist[NB];   // 16 KB (overlaid by gbuf later)
    __shared__ float s_edge[16][2];                  // lane-0 x.x per (wave, chunk)
    __shared__ float s_red[8][16];                   // 8 quantities x 16 waves
    __shared__ float s_fstat[6];
    __shared__ int   s_istat[2];
    __shared__ uint32_t s_wsum[16];
    __shared__ int   s_tbin[4], s_tbelow[4], s_tcnt[4];
    __shared__ int   s_gcnt[4];
    __shared__ float s_qv[4];
    __shared__ int   s_sel[2];

    const int tid  = threadIdx.x;
    const int lane = tid & 63;
    const int wid  = tid >> 6;
    const int bid  = blockIdx.x;
    const int b = bid >> 5;          // C == 32
    const int c = bid & 31;

    const float* row  = data + (size_t)bid * L_LEN;
    const int*   mrow = mask + (size_t)b  * L_LEN;

    // ---- Phase A: clear hist, coalesced load + sentinel mask, publish edges ----
    {
        uint4 z = make_uint4(0u, 0u, 0u, 0u);
        *reinterpret_cast<uint4*>(&s_hist[tid * 4]) = z;   // 4096/1024 = 4 bins/thread
    }
    float4 xs[2];
#pragma unroll
    for (int k = 0; k < 2; ++k) {
        const int g = k * (NT * 4) + tid * 4;
        const float4 v = *reinterpret_cast<const float4*>(row + g);
        const int4   m = *reinterpret_cast<const int4*>(mrow + g);
        float4 w;
        w.x = m.x ? v.x : FMAX;
        w.y = m.y ? v.y : FMAX;
        w.z = m.z ? v.z : FMAX;
        w.w = m.w ? v.w : FMAX;
        xs[k] = w;
        if (lane == 0) s_edge[wid][k] = w.x;
    }
    __syncthreads();

    // ---- Phase B: fused branchless stats + histogram (sentinels included) ----
    float sum = 0.f, sumsq = 0.f, dsum = 0.f, dsumsq = 0.f;
    float mn = FMAX, mx = -FMAX;
    int cnt = 0, dcnt = 0;

#pragma unroll
    for (int k = 0; k < 2; ++k) {
        const float4 x = xs[k];
        float nxt = __shfl_down(x.x, 1, 64);     // lane l -> lane l+1's x.x
        if (lane == 63)
            nxt = (wid < 15) ? s_edge[wid + 1][k]
                             : (k == 0 ? s_edge[0][1] : FMAX);
#define DO_E(X, Y) do {                                                       \
            const float x_ = (X), y_ = (Y);                                   \
            const bool v_ = (x_ != FMAX);                                     \
            const float xv_ = v_ ? x_ : 0.f;                                  \
            sum += xv_; sumsq = fmaf(xv_, xv_, sumsq);                        \
            mn = fminf(mn, x_);                                               \
            mx = fmaxf(mx, v_ ? x_ : -FMAX);                                  \
            cnt += v_;                                                        \
            atomicAdd(&s_hist[fkey(x_) >> 20], 1u);                           \
            const bool dv_ = v_ && (y_ != FMAX);                              \
            const float d_ = dv_ ? (y_ - x_) : 0.f;                           \
            dsum += d_; dsumsq = fmaf(d_, d_, dsumsq);                        \
            dcnt += dv_;                                                      \
        } while (0)
        DO_E(x.x, x.y);
        DO_E(x.y, x.z);
        DO_E(x.z, x.w);
        DO_E(x.w, nxt);
#undef DO_E
    }

    // wave shuffle reduce (8 quantities), then cross-wave via s_red
#pragma unroll
    for (int off = 32; off > 0; off >>= 1) {
        sum    += __shfl_down(sum, off, 64);
        sumsq  += __shfl_down(sumsq, off, 64);
        dsum   += __shfl_down(dsum, off, 64);
        dsumsq += __shfl_down(dsumsq, off, 64);
        mn = fminf(mn, __shfl_down(mn, off, 64));
        mx = fmaxf(mx, __shfl_down(mx, off, 64));
        cnt  += __shfl_down(cnt, off, 64);
        dcnt += __shfl_down(dcnt, off, 64);
    }
    if (lane == 0) {
        s_red[0][wid] = sum;
        s_red[1][wid] = sumsq;
        s_red[2][wid] = dsum;
        s_red[3][wid] = dsumsq;
        s_red[4][wid] = mn;
        s_red[5][wid] = mx;
        s_red[6][wid] = __int_as_float(cnt);
        s_red[7][wid] = __int_as_float(dcnt);
    }
    __syncthreads();          // also orders all histogram atomics before the scan
    if (tid < 8) {
        if (tid < 4) {
            float a = 0.f;
            for (int w = 0; w < 16; ++w) a += s_red[tid][w];
            s_fstat[tid] = a;
        } else if (tid == 4) {
            float a = FMAX;
            for (int w = 0; w < 16; ++w) a = fminf(a, s_red[4][w]);
            s_fstat[4] = a;
        } else if (tid == 5) {
            float a = -FMAX;
            for (int w = 0; w < 16; ++w) a = fmaxf(a, s_red[5][w]);
            s_fstat[5] = a;
        } else {
            int a = 0;
            for (int w = 0; w < 16; ++w) a += __float_as_int(s_red[tid][w]);
            s_istat[tid - 6] = a;
        }
    }
    __syncthreads();

    const float tsum = s_fstat[0], tsumsq = s_fstat[1];
    const float tdsum = s_fstat[2], tdsumsq = s_fstat[3];
    const float tmn = s_fstat[4], tmx = s_fstat[5];
    const int n = s_istat[0], nd = s_istat[1];

    // ---- Phase C: exact q25 / q75 ----
    float q25 = 0.f, q75 = 0.f;
    if (n > 0 && tmn == tmx) {
        q25 = q75 = tmn;
    } else if (n > 0) {
        const float pos25 = 0.25f * (float)(n - 1);
        const float pos75 = 0.75f * (float)(n - 1);
        const int l25 = (int)floorf(pos25), h25 = (int)ceilf(pos25);
        const int l75 = (int)floorf(pos75), h75 = (int)ceilf(pos75);
        const float frac25 = pos25 - (float)l25;
        const float frac75 = pos75 - (float)l75;
        int ranks[4] = { l25, h25, l75, h75 };

        // scan: thread owns 4 bins
        const int base4 = tid * 4;
        const uint4 cb4 = *reinterpret_cast<const uint4*>(&s_hist[base4]);
        const uint32_t lt = cb4.x + cb4.y + cb4.z + cb4.w;
        uint32_t incl = lt;
#pragma unroll
        for (int off = 1; off < 64; off <<= 1) {
            uint32_t up = __shfl_up(incl, off, 64);
            if (lane >= off) incl += up;
        }
        if (lane == 63) s_wsum[wid] = incl;
        __syncthreads();
        uint32_t wpre = 0;
        for (int w = 0; w < 16; ++w) wpre += (w < wid) ? s_wsum[w] : 0u;
        uint32_t run = wpre + incl - lt;   // exclusive prefix of this thread's bins

        const uint32_t cl[4] = { cb4.x, cb4.y, cb4.z, cb4.w };
#pragma unroll
        for (int j = 0; j < 4; ++j) {
            const uint32_t excl = run, inc = run + cl[j];
#pragma unroll
            for (int t = 0; t < 4; ++t) {
                const uint32_t r = (uint32_t)ranks[t];
                if (r >= excl && r < inc) {
                    s_tbin[t] = base4 + j;
                    s_tbelow[t] = (int)excl;
                    s_tcnt[t] = (int)cl[j];
                }
            }
            run = inc;
        }
        if (tid < 4) s_gcnt[tid] = 0;
        __syncthreads();

        // gather candidates from registers (sentinels included; exact per reference)
        float* gbuf = reinterpret_cast<float*>(s_hist);   // overlay, 4 x CAP floats
        const int tb0 = s_tbin[0], tb1 = s_tbin[1], tb2 = s_tbin[2], tb3 = s_tbin[3];
#pragma unroll
        for (int k = 0; k < 2; ++k) {
            const float4 x = xs[k];
#define DO_G(X) do {                                                          \
                const float x_ = (X);                                         \
                const int bn_ = (int)(fkey(x_) >> 20);                        \
                if (bn_ == tb0) { int i_ = atomicAdd(&s_gcnt[0], 1); if (i_ < CAP) gbuf[0 * CAP + i_] = x_; } \
                if (bn_ == tb1) { int i_ = atomicAdd(&s_gcnt[1], 1); if (i_ < CAP) gbuf[1 * CAP + i_] = x_; } \
                if (bn_ == tb2) { int i_ = atomicAdd(&s_gcnt[2], 1); if (i_ < CAP) gbuf[2 * CAP + i_] = x_; } \
                if (bn_ == tb3) { int i_ = atomicAdd(&s_gcnt[3], 1); if (i_ < CAP) gbuf[3 * CAP + i_] = x_; } \
            } while (0)
            DO_G(x.x); DO_G(x.y); DO_G(x.z); DO_G(x.w);
#undef DO_G
        }
        __syncthreads();

        // counting-rank select inside each gathered bin
#pragma unroll
        for (int t = 0; t < 4; ++t) {
            const int k = s_tcnt[t];
            if (k <= CAP) {
                const int rin = ranks[t] - s_tbelow[t];
                if (tid < k) {
                    const float xi = gbuf[t * CAP + tid];
                    int cless = 0;
                    for (int j = 0; j < k; ++j) {
                        const float y = gbuf[t * CAP + j];
                        cless += (y < xi || (y == xi && j < tid)) ? 1 : 0;
                    }
                    if (cless == rin) s_qv[t] = xi;
                }
            }
        }
        __syncthreads();

        // exact radix-select fallback (rare: only if a target bin > CAP)
        for (int t = 0; t < 4; ++t) {
            if (s_tcnt[t] > CAP) {
                uint32_t prefix = 0u, pmask = 0u;
                int r = ranks[t];
                for (int shift = 24; shift >= 0; shift -= 8) {
                    if (tid < 256) s_hist[tid] = 0u;
                    __syncthreads();
#pragma unroll
                    for (int k = 0; k < 2; ++k) {
                        const float4 x = xs[k];
#define DO_R(X) do {                                                          \
                            const uint32_t k_ = fkey(X);                      \
                            if ((k_ & pmask) == prefix)                       \
                                atomicAdd(&s_hist[(k_ >> shift) & 0xFFu], 1u);\
                        } while (0)
                        DO_R(x.x); DO_R(x.y); DO_R(x.z); DO_R(x.w);
#undef DO_R
                    }
                    __syncthreads();
                    uint32_t cb = (tid < 256) ? s_hist[tid] : 0u;
                    for (int off = 1; off < 256; off <<= 1) {
                        uint32_t vv = 0u, add = 0u;
                        if (tid < 256) {
                            vv = s_hist[tid];
                            if (tid >= off) add = s_hist[tid - off];
                        }
                        __syncthreads();
                        if (tid < 256) s_hist[tid] = vv + add;
                        __syncthreads();
                    }
                    if (tid < 256) {
                        const uint32_t incl2 = s_hist[tid];
                        const uint32_t excl2 = incl2 - cb;
                        if ((uint32_t)r >= excl2 && (uint32_t)r < incl2) {
                            s_sel[0] = tid;
                            s_sel[1] = (int)excl2;
                        }
                    }
                    __syncthreads();
                    prefix |= ((uint32_t)s_sel[0]) << shift;
                    pmask  |= 0xFFu << shift;
                    r -= s_sel[1];
                    __syncthreads();
                }
                if (tid == 0) {
                    const uint32_t u = (prefix & 0x80000000u) ? (prefix ^ 0x80000000u) : ~prefix;
                    s_qv[t] = __uint_as_float(u);
                }
                __syncthreads();
            }
        }
        __syncthreads();

        q25 = s_qv[0] + frac25 * (s_qv[1] - s_qv[0]);
        q75 = s_qv[2] + frac75 * (s_qv[3] - s_qv[2]);
    }

    // ---- epilogue ----
    if (tid == 0) {
        const float fc = (float)n;
        const float mean = (n > 0) ? tsum / fc : 0.f;
        const float var  = (n > 0) ? fmaxf(tsumsq / fc - mean * mean, 0.f) : 0.f;
        const float stdv = sqrtf(var);
        const float dmean = (nd > 0) ? tdsum / (float)nd : 0.f;
        const float dvar  = (nd > 0) ? fmaxf(tdsumsq / (float)nd - dmean * dmean, 0.f) : 0.f;
        const float dstd  = sqrtf(dvar);
        const float energy = tsumsq;
        const float rms = (n > 0) ? sqrtf(tsumsq / fc) : 0.f;

        float* o = out + (size_t)b * 320 + c;
        o[0 * 32] = mean;
        o[1 * 32] = stdv;
        o[2 * 32] = tmx;
        o[3 * 32] = tmn;
        o[4 * 32] = q25;
        o[5 * 32] = q75;
        o[6 * 32] = dmean;
        o[7 * 32] = dstd;
        o[8 * 32] = energy;
        o[9 * 32] = rms;
    }
}

extern "C" void kernel_launch(void* const* d_in, const int* in_sizes, int n_in,
                              void* d_out, int out_size, void* d_ws, size_t ws_size,
                              hipStream_t stream) {
    const float* data = (const float*)d_in[0];
    const int*   mask = (const int*)d_in[1];
    float*       out  = (float*)d_out;
    stats_kernel<<<dim3(128 * 32), dim3(NT), 0, stream>>>(data, mask, out);
}

// Round 6
// 282.010 us; speedup vs baseline: 1.3553x; 1.3553x over previous
//
#include <hip/hip_runtime.h>
#include <float.h>
#include <stdint.h>

// StatisticExtractor: B=128, C=32, L=8192.
// One 512-thread block per (b,c) row. Row in REGISTERS (4 float4/thread,
// chunked-coalesced). Invalid -> FLT_MAX sentinel. Pass1: branchless stats
// (incl min/max). Pass2: value-range 2048-bin histogram from registers
// (valid only). Shuffle scan -> gather target bins -> O(k^2) exact select;
// bit-exact radix fallback. launch_bounds(512,4): 128-VGPR cap, no spill,
// 2 blocks/CU so barrier phases overlap across blocks.

#define L_LEN 8192
#define NT    512
#define NCH   4      // chunks; elements/thread = NCH*4 = 16
#define NB    2048   // histogram bins over [min,max]
#define CAP   256    // max gathered candidates per target bin
#define FMAX  FLT_MAX

__device__ __forceinline__ uint32_t fkey(float x) {
    uint32_t u = __float_as_uint(x);
    return (u & 0x80000000u) ? ~u : (u | 0x80000000u);   // monotone total order
}

__global__ __launch_bounds__(NT, 4)
void stats_kernel(const float* __restrict__ data,
                  const int* __restrict__ mask,
                  float* __restrict__ out)
{
    __shared__ __align__(16) uint32_t s_hist[NB];   // 8 KB (overlaid by gbuf later)
    __shared__ float s_edge[8][NCH];                 // lane-0 x.x per (wave, chunk)
    __shared__ float s_red[8][8];                    // 8 quantities x 8 waves
    __shared__ float s_fstat[6];
    __shared__ int   s_istat[2];
    __shared__ uint32_t s_wsum[8];
    __shared__ int   s_tbin[4], s_tbelow[4], s_tcnt[4];
    __shared__ int   s_gcnt[4];
    __shared__ float s_qv[4];
    __shared__ int   s_sel[2];

    const int tid  = threadIdx.x;
    const int lane = tid & 63;
    const int wid  = tid >> 6;
    const int bid  = blockIdx.x;
    const int b = bid >> 5;          // C == 32
    const int c = bid & 31;

    const float* row  = data + (size_t)bid * L_LEN;
    const int*   mrow = mask + (size_t)b  * L_LEN;

    // ---- Phase A: clear hist, coalesced load + sentinel mask, publish edges ----
    {
        uint4 z = make_uint4(0u, 0u, 0u, 0u);
        *reinterpret_cast<uint4*>(&s_hist[tid * 4]) = z;   // 2048/512 = 4 bins/thread
    }
    float4 xs[NCH];
#pragma unroll
    for (int k = 0; k < NCH; ++k) {
        const int g = k * (NT * 4) + tid * 4;
        const float4 v = *reinterpret_cast<const float4*>(row + g);
        const int4   m = *reinterpret_cast<const int4*>(mrow + g);
        float4 w;
        w.x = m.x ? v.x : FMAX;
        w.y = m.y ? v.y : FMAX;
        w.z = m.z ? v.z : FMAX;
        w.w = m.w ? v.w : FMAX;
        xs[k] = w;
        if (lane == 0) s_edge[wid][k] = w.x;
    }
    __syncthreads();

    // ---- Phase B: fused branchless stats (incl min/max) + diff stats ----
    float sum = 0.f, sumsq = 0.f, dsum = 0.f, dsumsq = 0.f;
    float mn = FMAX, mx = -FMAX;
    int cnt = 0, dcnt = 0;

#pragma unroll
    for (int k = 0; k < NCH; ++k) {
        const float4 x = xs[k];
        float nxt = __shfl_down(x.x, 1, 64);     // lane l gets lane l+1's x.x
        if (lane == 63)
            nxt = (wid < 7) ? s_edge[wid + 1][k]
                            : (k < NCH - 1 ? s_edge[0][k + 1] : FMAX);
#define DO_E(X, Y) do {                                                       \
            const float x_ = (X), y_ = (Y);                                   \
            const bool v_ = (x_ != FMAX);                                     \
            const float xv_ = v_ ? x_ : 0.f;                                  \
            sum += xv_; sumsq = fmaf(xv_, xv_, sumsq);                        \
            mn = fminf(mn, x_);                                               \
            mx = fmaxf(mx, v_ ? x_ : -FMAX);                                  \
            cnt += v_;                                                        \
            const bool dv_ = v_ && (y_ != FMAX);                              \
            const float d_ = dv_ ? (y_ - x_) : 0.f;                           \
            dsum += d_; dsumsq = fmaf(d_, d_, dsumsq);                        \
            dcnt += dv_;                                                      \
        } while (0)
        DO_E(x.x, x.y);
        DO_E(x.y, x.z);
        DO_E(x.z, x.w);
        DO_E(x.w, nxt);
#undef DO_E
    }

    // wave shuffle reduce (8 quantities), then cross-wave via s_red
#pragma unroll
    for (int off = 32; off > 0; off >>= 1) {
        sum    += __shfl_down(sum, off, 64);
        sumsq  += __shfl_down(sumsq, off, 64);
        dsum   += __shfl_down(dsum, off, 64);
        dsumsq += __shfl_down(dsumsq, off, 64);
        mn = fminf(mn, __shfl_down(mn, off, 64));
        mx = fmaxf(mx, __shfl_down(mx, off, 64));
        cnt  += __shfl_down(cnt, off, 64);
        dcnt += __shfl_down(dcnt, off, 64);
    }
    if (lane == 0) {
        s_red[0][wid] = sum;
        s_red[1][wid] = sumsq;
        s_red[2][wid] = dsum;
        s_red[3][wid] = dsumsq;
        s_red[4][wid] = mn;
        s_red[5][wid] = mx;
        s_red[6][wid] = __int_as_float(cnt);
        s_red[7][wid] = __int_as_float(dcnt);
    }
    __syncthreads();
    if (tid < 8) {
        if (tid < 4) {
            float a = 0.f;
            for (int w = 0; w < 8; ++w) a += s_red[tid][w];
            s_fstat[tid] = a;
        } else if (tid == 4) {
            float a = FMAX;
            for (int w = 0; w < 8; ++w) a = fminf(a, s_red[4][w]);
            s_fstat[4] = a;
        } else if (tid == 5) {
            float a = -FMAX;
            for (int w = 0; w < 8; ++w) a = fmaxf(a, s_red[5][w]);
            s_fstat[5] = a;
        } else {
            int a = 0;
            for (int w = 0; w < 8; ++w) a += __float_as_int(s_red[tid][w]);
            s_istat[tid - 6] = a;
        }
    }
    __syncthreads();

    const float tsum = s_fstat[0], tsumsq = s_fstat[1];
    const float tdsum = s_fstat[2], tdsumsq = s_fstat[3];
    const float tmn = s_fstat[4], tmx = s_fstat[5];
    const int n = s_istat[0], nd = s_istat[1];

    // ---- Phase C: exact q25 / q75 via value-range histogram select ----
    float q25 = 0.f, q75 = 0.f;
    if (n > 0 && tmn == tmx) {
        q25 = q75 = tmn;
    } else if (n > 0) {
        const float pos25 = 0.25f * (float)(n - 1);
        const float pos75 = 0.75f * (float)(n - 1);
        const int l25 = (int)floorf(pos25), h25 = (int)ceilf(pos25);
        const int l75 = (int)floorf(pos75), h75 = (int)ceilf(pos75);
        const float frac25 = pos25 - (float)l25;
        const float frac75 = pos75 - (float)l75;
        int ranks[4] = { l25, h25, l75, h75 };

        // 1) histogram from registers (valid only; binning weakly monotone -> exact)
        const float scale = (float)NB / (tmx - tmn);
#pragma unroll
        for (int k = 0; k < NCH; ++k) {
            const float4 x = xs[k];
#define DO_H(X) do {                                                          \
                const float x_ = (X);                                         \
                if (x_ != FMAX) {                                             \
                    int bn_ = (int)((x_ - tmn) * scale);                      \
                    bn_ = bn_ < 0 ? 0 : (bn_ > NB - 1 ? NB - 1 : bn_);        \
                    atomicAdd(&s_hist[bn_], 1u);                              \
                }                                                             \
            } while (0)
            DO_H(x.x); DO_H(x.y); DO_H(x.z); DO_H(x.w);
#undef DO_H
        }
        __syncthreads();

        // 2) scan: thread owns 4 bins; wave shuffle scan + cross-wave prefix
        const int base4 = tid * 4;
        const uint4 cb4 = *reinterpret_cast<const uint4*>(&s_hist[base4]);
        const uint32_t lt = cb4.x + cb4.y + cb4.z + cb4.w;
        uint32_t incl = lt;
#pragma unroll
        for (int off = 1; off < 64; off <<= 1) {
            uint32_t up = __shfl_up(incl, off, 64);
            if (lane >= off) incl += up;
        }
        if (lane == 63) s_wsum[wid] = incl;
        __syncthreads();
        uint32_t wpre = 0;
        for (int w = 0; w < 8; ++w) wpre += (w < wid) ? s_wsum[w] : 0u;
        uint32_t run = wpre + incl - lt;

        const uint32_t cl[4] = { cb4.x, cb4.y, cb4.z, cb4.w };
#pragma unroll
        for (int j = 0; j < 4; ++j) {
            const uint32_t excl = run, inc = run + cl[j];
#pragma unroll
            for (int t = 0; t < 4; ++t) {
                const uint32_t r = (uint32_t)ranks[t];
                if (r >= excl && r < inc) {
                    s_tbin[t] = base4 + j;
                    s_tbelow[t] = (int)excl;
                    s_tcnt[t] = (int)cl[j];
                }
            }
            run = inc;
        }
        if (tid < 4) s_gcnt[tid] = 0;
        __syncthreads();

        // 3) gather candidates of the (<=4) target bins from registers
        float* gbuf = reinterpret_cast<float*>(s_hist);   // overlay, 4 x CAP floats
        const int tb0 = s_tbin[0], tb1 = s_tbin[1], tb2 = s_tbin[2], tb3 = s_tbin[3];
#pragma unroll
        for (int k = 0; k < NCH; ++k) {
            const float4 x = xs[k];
#define DO_G(X) do {                                                          \
                const float x_ = (X);                                         \
                if (x_ != FMAX) {                                             \
                    int bn_ = (int)((x_ - tmn) * scale);                      \
                    bn_ = bn_ < 0 ? 0 : (bn_ > NB - 1 ? NB - 1 : bn_);        \
                    if (bn_ == tb0) { int i_ = atomicAdd(&s_gcnt[0], 1); if (i_ < CAP) gbuf[0 * CAP + i_] = x_; } \
                    if (bn_ == tb1) { int i_ = atomicAdd(&s_gcnt[1], 1); if (i_ < CAP) gbuf[1 * CAP + i_] = x_; } \
                    if (bn_ == tb2) { int i_ = atomicAdd(&s_gcnt[2], 1); if (i_ < CAP) gbuf[2 * CAP + i_] = x_; } \
                    if (bn_ == tb3) { int i_ = atomicAdd(&s_gcnt[3], 1); if (i_ < CAP) gbuf[3 * CAP + i_] = x_; } \
                }                                                             \
            } while (0)
            DO_G(x.x); DO_G(x.y); DO_G(x.z); DO_G(x.w);
#undef DO_G
        }
        __syncthreads();

        // 4) counting-rank select inside each gathered bin (k expected ~6)
#pragma unroll
        for (int t = 0; t < 4; ++t) {
            const int k = s_tcnt[t];
            if (k <= CAP) {
                const int rin = ranks[t] - s_tbelow[t];
                if (tid < k) {
                    const float xi = gbuf[t * CAP + tid];
                    int cless = 0;
                    for (int j = 0; j < k; ++j) {
                        const float y = gbuf[t * CAP + j];
                        cless += (y < xi || (y == xi && j < tid)) ? 1 : 0;
                    }
                    if (cless == rin) s_qv[t] = xi;
                }
            }
        }
        __syncthreads();

        // 5) exact radix-select fallback (only if a target bin > CAP).
        //    Sentinels participate but sort above all targets (r < n) -> exact.
        for (int t = 0; t < 4; ++t) {
            if (s_tcnt[t] > CAP) {
                uint32_t prefix = 0u, pmask = 0u;
                int r = ranks[t];
                for (int shift = 24; shift >= 0; shift -= 8) {
                    if (tid < 256) s_hist[tid] = 0u;
                    __syncthreads();
#pragma unroll
                    for (int k = 0; k < NCH; ++k) {
                        const float4 x = xs[k];
#define DO_R(X) do {                                                          \
                            const uint32_t k_ = fkey(X);                      \
                            if ((k_ & pmask) == prefix)                       \
                                atomicAdd(&s_hist[(k_ >> shift) & 0xFFu], 1u);\
                        } while (0)
                        DO_R(x.x); DO_R(x.y); DO_R(x.z); DO_R(x.w);
#undef DO_R
                    }
                    __syncthreads();
                    uint32_t cb = (tid < 256) ? s_hist[tid] : 0u;
                    for (int off = 1; off < 256; off <<= 1) {
                        uint32_t vv = 0u, add = 0u;
                        if (tid < 256) {
                            vv = s_hist[tid];
                            if (tid >= off) add = s_hist[tid - off];
                        }
                        __syncthreads();
                        if (tid < 256) s_hist[tid] = vv + add;
                        __syncthreads();
                    }
                    if (tid < 256) {
                        const uint32_t incl2 = s_hist[tid];
                        const uint32_t excl2 = incl2 - cb;
                        if ((uint32_t)r >= excl2 && (uint32_t)r < incl2) {
                            s_sel[0] = tid;
                            s_sel[1] = (int)excl2;
                        }
                    }
                    __syncthreads();
                    prefix |= ((uint32_t)s_sel[0]) << shift;
                    pmask  |= 0xFFu << shift;
                    r -= s_sel[1];
                    __syncthreads();
                }
                if (tid == 0) {
                    const uint32_t u = (prefix & 0x80000000u) ? (prefix ^ 0x80000000u) : ~prefix;
                    s_qv[t] = __uint_as_float(u);
                }
                __syncthreads();
            }
        }
        __syncthreads();

        q25 = s_qv[0] + frac25 * (s_qv[1] - s_qv[0]);
        q75 = s_qv[2] + frac75 * (s_qv[3] - s_qv[2]);
    }

    // ---- epilogue ----
    if (tid == 0) {
        const float fc = (float)n;
        const float mean = (n > 0) ? tsum / fc : 0.f;
        const float var  = (n > 0) ? fmaxf(tsumsq / fc - mean * mean, 0.f) : 0.f;
        const float stdv = sqrtf(var);
        const float dmean = (nd > 0) ? tdsum / (float)nd : 0.f;
        const float dvar  = (nd > 0) ? fmaxf(tdsumsq / (float)nd - dmean * dmean, 0.f) : 0.f;
        const float dstd  = sqrtf(dvar);
        const float energy = tsumsq;
        const float rms = (n > 0) ? sqrtf(tsumsq / fc) : 0.f;

        float* o = out + (size_t)b * 320 + c;
        o[0 * 32] = mean;
        o[1 * 32] = stdv;
        o[2 * 32] = tmx;
        o[3 * 32] = tmn;
        o[4 * 32] = q25;
        o[5 * 32] = q75;
        o[6 * 32] = dmean;
        o[7 * 32] = dstd;
        o[8 * 32] = energy;
        o[9 * 32] = rms;
    }
}

extern "C" void kernel_launch(void* const* d_in, const int* in_sizes, int n_in,
                              void* d_out, int out_size, void* d_ws, size_t ws_size,
                              hipStream_t stream) {
    const float* data = (const float*)d_in[0];
    const int*   mask = (const int*)d_in[1];
    float*       out  = (float*)d_out;
    stats_kernel<<<dim3(128 * 32), dim3(NT), 0, stream>>>(data, mask, out);
}